// Round 14
// baseline (1127.701 us; speedup 1.0000x reference)
//
#include <hip/hip_runtime.h>
#include <math.h>

#define H 2048
#define IDIM 5632
#define NE 8
#define TT 2048            // tokens = 2*1024
#define LDW1 (2 * IDIM)    // 11264
#define NK1 (H / 64)       // 32
#define NK2 (IDIM / 64)    // 88

typedef __bf16 bf16x8 __attribute__((ext_vector_type(8)));
typedef float f32x4 __attribute__((ext_vector_type(4)));

__device__ __forceinline__ unsigned short f2bf(float f) {
    unsigned int u = __builtin_bit_cast(unsigned int, f);
    u += 0x7FFFu + ((u >> 16) & 1u);   // round-to-nearest-even
    return (unsigned short)(u >> 16);
}

// HW convert: compiler emits v_cvt_pk_bf16_f32 from paired casts (RTNE)
__device__ __forceinline__ unsigned int pk2(float a, float b) {
    __bf16 x = (__bf16)a, y = (__bf16)b;
    unsigned short lo = __builtin_bit_cast(unsigned short, x);
    unsigned short hi = __builtin_bit_cast(unsigned short, y);
    return (unsigned int)lo | ((unsigned int)hi << 16);
}

__device__ __forceinline__ void gload_lds16(const void* g, void* l) {
    __builtin_amdgcn_global_load_lds(
        (const __attribute__((address_space(1))) void*)g,
        (__attribute__((address_space(3))) void*)l, 16, 0, 0);
}

// ---------------- x (fp32) -> bf16 ----------------
__global__ void cvt_x_kernel(const float* __restrict__ x, unsigned short* __restrict__ xb) {
    int i = blockIdx.x * blockDim.x + threadIdx.x;
    float4 v = reinterpret_cast<const float4*>(x)[i];
    ushort4 o;
    o.x = f2bf(v.x); o.y = f2bf(v.y); o.z = f2bf(v.z); o.w = f2bf(v.w);
    reinterpret_cast<ushort4*>(xb)[i] = o;
}

// ---------------- router: fp64 logits, softmax, top-2, lists ----------------
__global__ void router_kernel(const float* __restrict__ x, const float* __restrict__ gw,
                              float* __restrict__ topw, int* __restrict__ cnt,
                              int* __restrict__ list) {
    int t = blockIdx.x;
    int lane = threadIdx.x;
    const float* xt = x + (size_t)t * H;
    double acc[NE];
#pragma unroll
    for (int e = 0; e < NE; ++e) acc[e] = 0.0;
    for (int h = lane; h < H; h += 64) {
        float xv = xt[h];
#pragma unroll
        for (int e = 0; e < NE; ++e) acc[e] += (double)xv * (double)gw[e * H + h];
    }
#pragma unroll
    for (int e = 0; e < NE; ++e) {
#pragma unroll
        for (int off = 32; off > 0; off >>= 1)
            acc[e] += __shfl_xor(acc[e], off, 64);
    }
    if (lane == 0) {
        double mx = acc[0];
#pragma unroll
        for (int e = 1; e < NE; ++e) mx = acc[e] > mx ? acc[e] : mx;
        double ex[NE], s = 0.0;
#pragma unroll
        for (int e = 0; e < NE; ++e) { ex[e] = exp(acc[e] - mx); s += ex[e]; }
        int e0 = 0; double b0 = ex[0];
#pragma unroll
        for (int e = 1; e < NE; ++e) if (ex[e] > b0) { b0 = ex[e]; e0 = e; }
        int e1 = -1; double b1 = -1.0;
#pragma unroll
        for (int e = 0; e < NE; ++e) if (e != e0 && ex[e] > b1) { b1 = ex[e]; e1 = e; }
        float p0 = (float)(b0 / s), p1 = (float)(b1 / s);
        float w0 = p0 / (p0 + p1), w1 = p1 / (p0 + p1);
        topw[t * 2 + 0] = w0;
        topw[t * 2 + 1] = w1;
        int pos0 = atomicAdd(&cnt[e0], 1); list[e0 * TT + pos0] = t * 2 + 0;
        int pos1 = atomicAdd(&cnt[e1], 1); list[e1 * TT + pos1] = t * 2 + 1;
    }
}

// ---------------- tile map (128-row tiles at [0..19]) ----------------
__global__ void setup_kernel(const int* __restrict__ cnt, int* __restrict__ tmap) {
    if (threadIdx.x == 0) {
        int a128 = 0, a256 = 0;
        tmap[0] = 0; tmap[20] = 0;
        for (int g = 0; g < 9; ++g) {
            int rows = (g == 0) ? TT : cnt[g - 1];
            tmap[10 + g] = rows;
            tmap[30 + g] = rows;
            a128 += (rows + 127) >> 7;
            a256 += (rows + 255) >> 8;
            tmap[g + 1] = a128;
            tmap[20 + g + 1] = a256;
        }
        tmap[19] = 0; tmap[39] = 0;
    }
}

// B staging: 8 float2 loads (consecutive cols), named array, static indices
#define LDB(BR, KT)                                                      \
    {                                                                    \
        _Pragma("unroll")                                                \
        for (int r_ = 0; r_ < 8; ++r_)                                   \
            BR[r_] = *reinterpret_cast<const float2*>(                   \
                bp + (size_t)((KT) * 64 + r_) * BST);                    \
    }
// cvt+pack+swizzled writes: 2 ds_write_b128 (cols c0, c0+1)
#define WRB(BR, NB)                                                      \
    {                                                                    \
        char* pbw_ = (char*)lds_b[NB];                                   \
        uint4 pk_;                                                       \
        pk_.x = pk2(BR[0].x, BR[1].x); pk_.y = pk2(BR[2].x, BR[3].x);    \
        pk_.z = pk2(BR[4].x, BR[5].x); pk_.w = pk2(BR[6].x, BR[7].x);    \
        *reinterpret_cast<uint4*>(pbw_ + bwa0) = pk_;                    \
        pk_.x = pk2(BR[0].y, BR[1].y); pk_.y = pk2(BR[2].y, BR[3].y);    \
        pk_.z = pk2(BR[4].y, BR[5].y); pk_.w = pk2(BR[6].y, BR[7].y);    \
        *reinterpret_cast<uint4*>(pbw_ + bwa1) = pk_;                    \
    }

// ============ GEMM1: 128 rows x 128 wcols (64 act), BK=64, fold-convert, 2 blk/CU =====
__global__ __launch_bounds__(512, 4)
void gemm1_kernel(const unsigned short* __restrict__ xb,
                  const float* __restrict__ base_gu,
                  const float* __restrict__ exp_gu,
                  const int* __restrict__ tmap,
                  const int* __restrict__ list,
                  unsigned short* __restrict__ actB,
                  unsigned short* __restrict__ actE) {
    __shared__ unsigned short lds_a[2][128 * 64];   // 16 KB each
    __shared__ unsigned short lds_b[2][128 * 64];   // 16 KB each
    __shared__ int s_arow[128];
    __shared__ int s_orow[128];
    __shared__ int sh[20];

    int tid = threadIdx.x;
    if (tid < 20) sh[tid] = tmap[tid];
    __syncthreads();
    int bid = blockIdx.x;
    int virt = (bid & 7) * 616 + (bid >> 3);     // 4928 = 8*616; jcols contiguous per XCD
    int jcol = virt / 56;                        // 0..87
    int rt = virt % 56;
    if (rt >= sh[9]) return;
    int g = 0;
    while (rt >= sh[g + 1]) ++g;
    int rows_g = sh[10 + g];
    int row0 = (rt - sh[g]) * 128;
    int n0a = jcol * 64;                         // act-col base

    if (tid < 128) {
        int r = row0 + tid;
        int arow = 0, orow = 0;
        if (r < rows_g) {
            if (g == 0) { arow = r; orow = r; }
            else { int e = list[(g - 1) * TT + r]; arow = e >> 1; orow = e; }
        }
        s_arow[tid] = arow;
        s_orow[tid] = orow;
    }
    __syncthreads();

    const float* W = (g == 0) ? base_gu : (exp_gu + (size_t)(g - 1) * H * LDW1);
    unsigned short* actPtr = (g == 0) ? actB : actE;
    const size_t BST = LDW1;

    // A: 2 gloads/tile; chunk = i*512+tid -> row=chunk>>3 (0..127), kc=chunk&7
    const unsigned short* asrc[2];
#pragma unroll
    for (int i = 0; i < 2; ++i) {
        int chunk = i * 512 + tid;
        int sA = chunk >> 3, kc = chunk & 7;
        asrc[i] = xb + (size_t)s_arow[sA] * H + ((kc ^ (sA & 7)) << 3);
    }
    int dstoffA = (tid >> 6) * 1024;

    // B: thread -> col pair c0=2cg (LDS cols), k rows ks*8..+7
    int cg = tid & 63, ks = tid >> 6;
    int c0 = 2 * cg;
    // LDS col c -> wcol: half=(c>>4)&1, acol = n0a + ((c>>5)<<4) + (c&15)
    int wcol0 = (((c0 >> 4) & 1) ? IDIM : 0) + n0a + ((c0 >> 5) << 4) + (c0 & 15);
    const float* bp = W + (size_t)(ks * 8) * LDW1 + wcol0;
    int bwa0 = c0 * 128 + ((ks ^ (c0 & 7)) << 4);
    int bwa1 = (c0 + 1) * 128 + ((ks ^ ((c0 + 1) & 7)) << 4);

    int wave = tid >> 6, lane = tid & 63;
    int wr = wave >> 2, wc = wave & 3;           // 2M x 4N; wave tile 64x32
    int arow0 = wr * 64 + (lane & 15);
    int bcol0 = wc * 32 + (lane & 15);
    int lxor = lane & 7;
    int kq = lane >> 4;

    f32x4 acc[4][2];
#pragma unroll
    for (int fm = 0; fm < 4; ++fm)
#pragma unroll
        for (int fn = 0; fn < 2; ++fn)
            acc[fm][fn] = (f32x4)(0.0f);

    auto stA = [&](int kt, int nb) {
#pragma unroll
        for (int i = 0; i < 2; ++i)
            gload_lds16(asrc[i] + kt * 64, (char*)lds_a[nb] + i * 8192 + dstoffA);
    };
    auto compute = [&](int buf) {
        const char* pa = (const char*)lds_a[buf];
        const char* pb = (const char*)lds_b[buf];
#pragma unroll
        for (int kh = 0; kh < 2; ++kh) {
            int slot = ((kq + kh * 4) ^ lxor) << 4;
            bf16x8 bF0 = *reinterpret_cast<const bf16x8*>(pb + bcol0 * 128 + slot);
            bf16x8 bF1 = *reinterpret_cast<const bf16x8*>(pb + (bcol0 + 16) * 128 + slot);
#pragma unroll
            for (int i = 0; i < 4; ++i) {
                bf16x8 aF = *reinterpret_cast<const bf16x8*>(pa + (arow0 + i * 16) * 128 + slot);
                acc[i][0] = __builtin_amdgcn_mfma_f32_16x16x32_bf16(aF, bF0, acc[i][0], 0, 0, 0);
                acc[i][1] = __builtin_amdgcn_mfma_f32_16x16x32_bf16(aF, bF1, acc[i][1], 0, 0, 0);
            }
        }
    };

    float2 brX[8];

    // prologue: tile 0 staged
    LDB(brX, 0)
    stA(0, 0);
    WRB(brX, 0)                      // implicit vmcnt(2) drains B(0); stA in flight
    asm volatile("s_waitcnt vmcnt(0) lgkmcnt(0)" ::: "memory");
    __builtin_amdgcn_sched_barrier(0);
    __builtin_amdgcn_s_barrier();

    for (int t = 0; t < NK1; ++t) {
        int buf = t & 1, nbuf = buf ^ 1;
        bool st = t + 1 < NK1;
        if (st) { LDB(brX, t + 1) stA(t + 1, nbuf); }
        compute(buf);
        if (st) { WRB(brX, nbuf) }   // implicit vmcnt(2): B loads covered by compute
        asm volatile("s_waitcnt vmcnt(0) lgkmcnt(0)" ::: "memory");
        __builtin_amdgcn_sched_barrier(0);
        __builtin_amdgcn_s_barrier();
    }

    int cq = lane >> 4, cr = lane & 15;
#pragma unroll
    for (int fm = 0; fm < 4; ++fm) {
#pragma unroll
        for (int r = 0; r < 4; ++r) {
            int rloc = wr * 64 + fm * 16 + cq * 4 + r;
            if (row0 + rloc < rows_g) {
                size_t orow = (size_t)s_orow[rloc];
                float gv = acc[fm][0][r];
                float uv = acc[fm][1][r];
                float sv = gv / (1.0f + __expf(-gv));
                int col = n0a + wc * 16 + cr;
                actPtr[orow * IDIM + col] = f2bf(sv * uv);
            }
        }
    }
}

// ============ GEMM2: 128 rows x 128 cols, BK=64, fold-convert, 2 blk/CU ============
__global__ __launch_bounds__(512, 4)
void gemm2_kernel(const unsigned short* __restrict__ actB,
                  const unsigned short* __restrict__ actE,
                  const float* __restrict__ base_dn,
                  const float* __restrict__ exp_dn,
                  const int* __restrict__ tmap,
                  const int* __restrict__ list,
                  float* __restrict__ outB,
                  float* __restrict__ yslot) {
    __shared__ unsigned short lds_a[2][128 * 64];
    __shared__ unsigned short lds_b[2][128 * 64];
    __shared__ int s_row[128];
    __shared__ int sh[20];

    int tid = threadIdx.x;
    if (tid < 20) sh[tid] = tmap[tid];
    __syncthreads();
    int bid = blockIdx.x;
    int virt = (bid & 7) * 112 + (bid >> 3);     // 896 = 8*112; 2 jcols per XCD
    int jcol = virt / 56;                        // 0..15
    int rt = virt % 56;
    if (rt >= sh[9]) return;
    int g = 0;
    while (rt >= sh[g + 1]) ++g;
    int rows_g = sh[10 + g];
    int row0 = (rt - sh[g]) * 128;
    int n0 = jcol * 128;

    if (tid < 128) {
        int r = row0 + tid;
        int rowi = 0;
        if (r < rows_g) rowi = (g == 0) ? r : list[(g - 1) * TT + r];
        s_row[tid] = rowi;
    }
    __syncthreads();

    const unsigned short* abase = (g == 0) ? actB : actE;
    const float* W = (g == 0) ? base_dn : (exp_dn + (size_t)(g - 1) * IDIM * H);
    float* obase = (g == 0) ? outB : yslot;
    const size_t BST = H;

    const unsigned short* asrc[2];
#pragma unroll
    for (int i = 0; i < 2; ++i) {
        int chunk = i * 512 + tid;
        int sA = chunk >> 3, kc = chunk & 7;
        asrc[i] = abase + (size_t)s_row[sA] * IDIM + ((kc ^ (sA & 7)) << 3);
    }
    int dstoffA = (tid >> 6) * 1024;

    int cg = tid & 63, ks = tid >> 6;
    int c0 = 2 * cg;
    const float* bp = W + (size_t)(ks * 8) * H + n0 + c0;
    int bwa0 = c0 * 128 + ((ks ^ (c0 & 7)) << 4);
    int bwa1 = (c0 + 1) * 128 + ((ks ^ ((c0 + 1) & 7)) << 4);

    int wave = tid >> 6, lane = tid & 63;
    int wr = wave >> 2, wc = wave & 3;
    int arow0 = wr * 64 + (lane & 15);
    int bcol0 = wc * 32 + (lane & 15);
    int lxor = lane & 7;
    int kq = lane >> 4;

    f32x4 acc[4][2];
#pragma unroll
    for (int fm = 0; fm < 4; ++fm)
#pragma unroll
        for (int fn = 0; fn < 2; ++fn)
            acc[fm][fn] = (f32x4)(0.0f);

    auto stA = [&](int kt, int nb) {
#pragma unroll
        for (int i = 0; i < 2; ++i)
            gload_lds16(asrc[i] + kt * 64, (char*)lds_a[nb] + i * 8192 + dstoffA);
    };
    auto compute = [&](int buf) {
        const char* pa = (const char*)lds_a[buf];
        const char* pb = (const char*)lds_b[buf];
#pragma unroll
        for (int kh = 0; kh < 2; ++kh) {
            int slot = ((kq + kh * 4) ^ lxor) << 4;
            bf16x8 bF0 = *reinterpret_cast<const bf16x8*>(pb + bcol0 * 128 + slot);
            bf16x8 bF1 = *reinterpret_cast<const bf16x8*>(pb + (bcol0 + 16) * 128 + slot);
#pragma unroll
            for (int i = 0; i < 4; ++i) {
                bf16x8 aF = *reinterpret_cast<const bf16x8*>(pa + (arow0 + i * 16) * 128 + slot);
                acc[i][0] = __builtin_amdgcn_mfma_f32_16x16x32_bf16(aF, bF0, acc[i][0], 0, 0, 0);
                acc[i][1] = __builtin_amdgcn_mfma_f32_16x16x32_bf16(aF, bF1, acc[i][1], 0, 0, 0);
            }
        }
    };

    float2 brX[8];

    LDB(brX, 0)
    stA(0, 0);
    WRB(brX, 0)
    asm volatile("s_waitcnt vmcnt(0) lgkmcnt(0)" ::: "memory");
    __builtin_amdgcn_sched_barrier(0);
    __builtin_amdgcn_s_barrier();

    for (int t = 0; t < NK2; ++t) {
        int buf = t & 1, nbuf = buf ^ 1;
        bool st = t + 1 < NK2;
        if (st) { LDB(brX, t + 1) stA(t + 1, nbuf); }
        compute(buf);
        if (st) { WRB(brX, nbuf) }
        asm volatile("s_waitcnt vmcnt(0) lgkmcnt(0)" ::: "memory");
        __builtin_amdgcn_sched_barrier(0);
        __builtin_amdgcn_s_barrier();
    }

    int cq = lane >> 4, cr = lane & 15;
#pragma unroll
    for (int fm = 0; fm < 4; ++fm) {
#pragma unroll
        for (int r = 0; r < 4; ++r) {
            int rloc = wr * 64 + fm * 16 + cq * 4 + r;
            if (row0 + rloc < rows_g) {
                size_t orow = (size_t)s_row[rloc];
#pragma unroll
                for (int fn = 0; fn < 2; ++fn) {
                    int col = n0 + wc * 32 + fn * 16 + cr;
                    obase[orow * H + col] = acc[fm][fn][r];
                }
            }
        }
    }
}

// ---------------- combine: out += w0*y0 + w1*y1 ----------------
__global__ void combine_kernel(float* __restrict__ out, const float* __restrict__ yslot,
                               const float* __restrict__ topw) {
    int i = blockIdx.x * blockDim.x + threadIdx.x;
    int t = i >> 9;
    int c = (i & 511) << 2;
    float w0 = topw[t * 2], w1 = topw[t * 2 + 1];
    float4 y0 = *reinterpret_cast<const float4*>(yslot + ((size_t)(2 * t) * H + c));
    float4 y1 = *reinterpret_cast<const float4*>(yslot + ((size_t)(2 * t + 1) * H + c));
    float4* po = reinterpret_cast<float4*>(out + ((size_t)t * H + c));
    float4 o = *po;
    o.x += w0 * y0.x + w1 * y1.x;
    o.y += w0 * y0.y + w1 * y1.y;
    o.z += w0 * y0.z + w1 * y1.z;
    o.w += w0 * y0.w + w1 * y1.w;
    *po = o;
}

extern "C" void kernel_launch(void* const* d_in, const int* in_sizes, int n_in,
                              void* d_out, int out_size, void* d_ws, size_t ws_size,
                              hipStream_t stream) {
    const float* x   = (const float*)d_in[0];
    const float* gw  = (const float*)d_in[1];
    const float* bgu = (const float*)d_in[2];
    const float* bdn = (const float*)d_in[3];
    const float* egu = (const float*)d_in[4];
    const float* edn = (const float*)d_in[5];
    float* out = (float*)d_out;
    char* ws = (char*)d_ws;

    unsigned short* xb   = (unsigned short*)(ws + 0);          //  8,388,608 B
    unsigned short* actB = (unsigned short*)(ws + 8388608);    // 23,068,672 B
    unsigned short* actE = (unsigned short*)(ws + 31457280);   // 46,137,344 B
    float* yslot         = (float*)(ws + 77594624);            // 33,554,432 B
    float* topw          = (float*)(ws + 111149056);
    int* cnt             = (int*)(ws + 111165440);
    int* list            = (int*)(ws + 111165696);
    int* tmap            = (int*)(ws + 111231232);

    hipMemsetAsync(cnt, 0, NE * sizeof(int), stream);
    cvt_x_kernel<<<4096, 256, 0, stream>>>(x, xb);
    router_kernel<<<TT, 64, 0, stream>>>(x, gw, topw, cnt, list);
    setup_kernel<<<1, 64, 0, stream>>>(cnt, tmap);
    // gemm1: 88 col-strips x up-to-56 row-tiles, XCD-pinned (4928 = 8*11*56)
    gemm1_kernel<<<4928, 512, 0, stream>>>(xb, bgu, egu, tmap, list, actB, actE);
    // gemm2: 16 col-strips x up-to-56 row-tiles (896 = 8*2*56)
    gemm2_kernel<<<896, 512, 0, stream>>>(actB, actE, bdn, edn, tmap, list, out, yslot);
    combine_kernel<<<4096, 256, 0, stream>>>(out, yslot, topw);
}